// Round 14
// baseline (428.238 us; speedup 1.0000x reference)
//
#include <hip/hip_runtime.h>
#include <hip/hip_bf16.h>
#include <math.h>

#define D 1024
#define NP 128
#define BS 2
#define GEO 64
#define TOPKN 18
#define NPAIR (BS*NP*NP)   // 32768

__device__ __forceinline__ float relu_(float x){ return fmaxf(x, 0.f); }
__device__ __forceinline__ unsigned short f2b(float x){
    __hip_bfloat16 h = __float2bfloat16(x);
    return *(unsigned short*)&h;
}
__device__ __forceinline__ float b2f(unsigned short u){
    return __uint_as_float((unsigned)u << 16);
}

typedef short bf16x8 __attribute__((ext_vector_type(8)));
typedef float f32x4  __attribute__((ext_vector_type(4)));

// async global->LDS, 16B per lane. LDS dest must be wave-uniform base + lane*16.
__device__ __forceinline__ void glds16(const unsigned short* g, unsigned short* l){
    __builtin_amdgcn_global_load_lds(
        (const __attribute__((address_space(1))) void*)g,
        (__attribute__((address_space(3))) void*)l,
        16, 0, 0);
}

// ------- geo embedding + 3x Linear(64,64) via MFMA (chunk-local, bf16 out) -------
#define GSTR 72
__global__ __launch_bounds__(256) void k_geo2(
    const float* __restrict__ prop,
    const float* __restrict__ gw1, const float* __restrict__ gb1,
    const float* __restrict__ gw2, const float* __restrict__ gb2,
    const float* __restrict__ gw3, const float* __restrict__ gb3,
    unsigned short* __restrict__ geoPc, int pofs)
{
    __shared__ unsigned short WT[3][GEO*GSTR];   // W^T bf16, padded: 27.6 KB
    __shared__ float gb[3][GEO];
    __shared__ unsigned short buf[4][GEO*GSTR];  // per-wave act tile: 36.9 KB
    int t = threadIdx.x, l = t & 63, w = t >> 6;

    for (int idx = t; idx < GEO*GEO; idx += 256) {
        int k = idx >> 6, n = idx & 63;          // W[k][n], coalesced over n
        WT[0][n*GSTR + k] = f2b(gw1[idx]);
        WT[1][n*GSTR + k] = f2b(gw2[idx]);
        WT[2][n*GSTR + k] = f2b(gw3[idx]);
    }
    if (t < GEO) { gb[0][t]=gb1[t]; gb[1][t]=gb2[t]; gb[2][t]=gb3[t]; }

    int plocal = blockIdx.x*256 + w*64;          // chunk-local pair base
    int pair0  = pofs + plocal;                  // global pair base
    int c = l;
    int p = c >> 4, s = c & 15, f = s & 7;
    float dm = expf((float)f * (6.907755278982137f/8.0f)); // 1000^(f/8)
    bool is_cos = (s & 8) != 0;
    float scale = 100.f / dm;

    int b  = pair0 >> 14;
    int ij = pair0 & 16383;
    int i  = ij >> 7;
    int j0 = ij & 127;
    float4 pi = *(const float4*)(prop + (size_t)(b*NP + i)*4);
    float wi  = pi.z-pi.x+1.f, hi_ = pi.w-pi.y+1.f;
    unsigned short* mybuf = buf[w];
    for (int r = 0; r < 64; ++r) {
        float4 pj = *(const float4*)(prop + (size_t)(b*NP + j0 + r)*4);
        float wj  = pj.z-pj.x+1.f, hj  = pj.w-pj.y+1.f;
        float pos;
        if      (p == 0) pos = (0.5f*(pi.x+pi.z) - 0.5f*(pj.x+pj.z)) / wj;
        else if (p == 1) pos = (0.5f*(pi.y+pi.w) - 0.5f*(pj.y+pj.w)) / hj;
        else if (p == 2) pos = wi / wj;
        else             pos = hi_ / hj;
        pos = logf(fmaxf(fabsf(pos), 1e-3f));
        float dv = pos * scale;
        mybuf[r*GSTR + c] = f2b(is_cos ? cosf(dv) : sinf(dv));
    }
    __syncthreads();

    int lr = l & 15, lq = l >> 4;
    #pragma unroll
    for (int layer = 0; layer < 3; ++layer) {
        const unsigned short* WTl = WT[layer];
        f32x4 acc[4][4];
        #pragma unroll
        for (int mi = 0; mi < 4; ++mi)
            #pragma unroll
            for (int ni = 0; ni < 4; ++ni)
                #pragma unroll
                for (int r = 0; r < 4; ++r) acc[mi][ni][r] = 0.f;
        #pragma unroll
        for (int kc = 0; kc < 2; ++kc) {
            bf16x8 af[4], bf[4];
            #pragma unroll
            for (int mi = 0; mi < 4; ++mi)
                af[mi] = *(const bf16x8*)(mybuf + (mi*16+lr)*GSTR + kc*32 + lq*8);
            #pragma unroll
            for (int ni = 0; ni < 4; ++ni)
                bf[ni] = *(const bf16x8*)(WTl + (ni*16+lr)*GSTR + kc*32 + lq*8);
            #pragma unroll
            for (int mi = 0; mi < 4; ++mi)
                #pragma unroll
                for (int ni = 0; ni < 4; ++ni)
                    acc[mi][ni] = __builtin_amdgcn_mfma_f32_16x16x32_bf16(af[mi], bf[ni], acc[mi][ni], 0, 0, 0);
        }
        __syncthreads();
        #pragma unroll
        for (int mi = 0; mi < 4; ++mi) {
            #pragma unroll
            for (int ni = 0; ni < 4; ++ni) {
                int col = ni*16 + lr;
                float bv = gb[layer][col];
                #pragma unroll
                for (int r = 0; r < 4; ++r) {
                    int row = mi*16 + lq*4 + r;
                    float v = acc[mi][ni][r] + bv;
                    if (layer < 2) {
                        mybuf[row*GSTR + col] = f2b(relu_(v));
                    } else {
                        geoPc[(size_t)(plocal + row)*GEO + col] = f2b(v);
                    }
                }
            }
        }
        __syncthreads();
    }
}

// ------------- batched weight transpose+bf16: 8 matrices, N=1024 cols -------------
struct WT8 {
    const float* src[8];
    unsigned short* dst[8];
    int kt[8];     // K/64
    int pre[9];    // prefix of tile counts (kt*16)
};
__global__ __launch_bounds__(256) void k_wTall(WT8 d)
{
    __shared__ float tile[64][65];
    int bid = blockIdx.x;
    int e = 0;
    while (e < 7 && bid >= d.pre[e+1]) ++e;
    int local = bid - d.pre[e];
    int bx = local & 15;      // n-tile (N=1024 -> 16 tiles)
    int by = local >> 4;      // k-tile
    int K = d.kt[e] * 64;
    const float* W = d.src[e];
    unsigned short* WT = d.dst[e];
    int t = threadIdx.x;
    int tc = t & 63, tr = t >> 6;
    #pragma unroll
    for (int r = tr; r < 64; r += 4)
        tile[r][tc] = W[(size_t)(by*64 + r)*1024 + bx*64 + tc];
    __syncthreads();
    #pragma unroll
    for (int r = tr; r < 64; r += 4)
        WT[(size_t)(bx*64 + r)*K + by*64 + tc] = f2b(tile[tc][r]);
}

// ---------------- split-K MFMA GEMM for M=256 layers ----------------
// NOTE (round 7 lesson): do NOT replace these split-K pairs with direct full-K
// kernels. Direct kernels launch <=256 blocks (<=1/CU, half-idle GPU) and expose
// global-load latency every K-step; measured +50 us total. Split-K's 512-1024
// blocks provide the in-kernel TLP that hides latency; launch gaps are small.
template<bool A_F32>
__global__ __launch_bounds__(256) void k_skmm(
    const void* __restrict__ A1v, const void* __restrict__ A2v,
    int K1, int K2,
    const unsigned short* __restrict__ BT0,
    const unsigned short* __restrict__ BT1,
    float* __restrict__ Cp,
    int KZ, int Kc, int N)
{
    __shared__ unsigned short As[16*32];
    __shared__ unsigned short Bs[128*32];
    int t = threadIdx.x;
    int m0 = blockIdx.x * 16;
    int n0 = blockIdx.y * 128;
    int bz = blockIdx.z;
    int kz = bz % KZ;
    int mat = bz / KZ;
    const unsigned short* BT = mat ? BT1 : BT0;
    int K = K1 + K2;
    int M = gridDim.x * 16;
    int w = t >> 6, l = t & 63;
    int lr = l & 15, lq = l >> 4;
    int arow = t >> 3, ak = (t & 7) * 4;
    int arow2 = t >> 2, ak2 = (t & 3) * 8;
    int brow = t >> 1, bk = (t & 1) * 16;
    f32x4 acc0 = {0.f,0.f,0.f,0.f}, acc1 = {0.f,0.f,0.f,0.f};
    for (int i = 0; i < Kc; i += 32) {
        int kg0 = kz*Kc + i;
        __syncthreads();
        if (A_F32) {
            if (t < 128) {
                int kg = kg0 + ak;
                const float* src = (kg < K1)
                    ? (const float*)A1v + (size_t)(m0+arow)*K1 + kg
                    : (const float*)A2v + (size_t)(m0+arow)*K2 + (kg - K1);
                float4 a4 = *(const float4*)src;
                ushort4 u;
                u.x=f2b(a4.x); u.y=f2b(a4.y); u.z=f2b(a4.z); u.w=f2b(a4.w);
                *(ushort4*)(As + arow*32 + ak) = u;
            }
        } else {
            if (t < 64) {
                const unsigned short* src = (const unsigned short*)A1v + (size_t)(m0+arow2)*K1 + kg0 + ak2;
                *(bf16x8*)(As + arow2*32 + ak2) = *(const bf16x8*)src;
            }
        }
        const unsigned short* srcb = BT + (size_t)(n0+brow)*K + kg0 + bk;
        *(bf16x8*)(Bs + brow*32 + bk)     = *(const bf16x8*)srcb;
        *(bf16x8*)(Bs + brow*32 + bk + 8) = *(const bf16x8*)(srcb + 8);
        __syncthreads();
        bf16x8 af = *(const bf16x8*)(As + lr*32 + lq*8);
        bf16x8 b0 = *(const bf16x8*)(Bs + (w*32      + lr)*32 + lq*8);
        bf16x8 b1 = *(const bf16x8*)(Bs + (w*32 + 16 + lr)*32 + lq*8);
        acc0 = __builtin_amdgcn_mfma_f32_16x16x32_bf16(af, b0, acc0, 0, 0, 0);
        acc1 = __builtin_amdgcn_mfma_f32_16x16x32_bf16(af, b1, acc1, 0, 0, 0);
    }
    float* Co = Cp + (size_t)bz*M*N;
    #pragma unroll
    for (int r = 0; r < 4; ++r) {
        int gr = m0 + lq*4 + r;
        Co[(size_t)gr*N + n0 + w*32      + lr] = acc0[r];
        Co[(size_t)gr*N + n0 + w*32 + 16 + lr] = acc1[r];
    }
}

// ---------------- reduce split-K partials: out = act(sum + bias) ----------------
template<bool RELU, bool OUT_BF16>
__global__ __launch_bounds__(256) void k_red(
    const float* __restrict__ Cp, int KZ,
    const float* __restrict__ bias,
    void* __restrict__ out0, void* __restrict__ out1,
    int MN, int N)
{
    int z = blockIdx.z;
    const float* C = Cp + (size_t)z*KZ*MN;
    void* out = z ? out1 : out0;
    int idx = (blockIdx.x*256 + threadIdx.x) * 4;
    f32x4 s = {0.f,0.f,0.f,0.f};
    for (int k = 0; k < KZ; ++k)
        s += *(const f32x4*)(C + (size_t)k*MN + idx);
    if (bias) s += *(const f32x4*)(bias + (idx & (N-1)));
    if (RELU) { s[0]=relu_(s[0]); s[1]=relu_(s[1]); s[2]=relu_(s[2]); s[3]=relu_(s[3]); }
    if (OUT_BF16) {
        ushort4 u; u.x=f2b(s[0]); u.y=f2b(s[1]); u.z=f2b(s[2]); u.w=f2b(s[3]);
        *(ushort4*)((unsigned short*)out + idx) = u;
    } else {
        float4 o; o.x=s[0]; o.y=s[1]; o.z=s[2]; o.w=s[3];
        *(float4*)((float*)out + idx) = o;
    }
}

// ===== 8-phase 256x256 bf16 MFMA GEMM (T1+T2+T3+T4+T5), C = act(A@B^T + bias) =====
// ROUND-4 SCHEDULE (measured best: ~78-80 us, MfmaUtil ~35.5, bank conflicts 0).
//
// TOPK epilogue v4 (round-12, measured 96.5 us vs v3's 114.8): layout
// TP[row 128][stride 257]; scan reads/publish/merge all land 2 lanes/bank.
// Scan = dep-free paired insertion; merge = static-index order-statistic.
//
// LDS swizzle (verified: conflicts 7.3M -> 0): phys = lo ^ ((row&7)<<4). Linear
// glds dest + inverse-swizzled global source + swizzled ds_read offsets (#21).

#define STG(g, lb) { glds16((g) + ssrc0, (lb) + sdst0); glds16((g) + ssrc1, (lb) + sdst1); }

#define MM8_PHASE(Q, LAH, LBH, STAGE_STMT, VM)                                  \
  {                                                                             \
    if ((Q) == 0 || (Q) == 2) {                                                 \
      const char* ah = (const char*)(LAH) + ((Q) == 2 ? 16384 : 0);             \
      _Pragma("unroll")                                                         \
      for (int mi = 0; mi < 4; ++mi) {                                          \
        af[mi][0] = *(const bf16x8*)(ah + aoff[mi][0]);                         \
        af[mi][1] = *(const bf16x8*)(ah + aoff[mi][1]);                         \
      }                                                                         \
    }                                                                           \
    if ((Q) != 2) {                                                             \
      const char* bh = (const char*)(LBH) + ((Q) == 1 ? 16384 : 0);             \
      _Pragma("unroll")                                                         \
      for (int ni = 0; ni < 2; ++ni) {                                          \
        bfr[ni][0] = *(const bf16x8*)(bh + boff[ni][0]);                        \
        bfr[ni][1] = *(const bf16x8*)(bh + boff[ni][1]);                        \
      }                                                                         \
    }                                                                           \
    STAGE_STMT;                                                                 \
    asm volatile("s_waitcnt vmcnt(" #VM ")" ::: "memory");                      \
    __builtin_amdgcn_s_barrier();                                               \
    asm volatile("" ::: "memory");                                              \
    __builtin_amdgcn_s_setprio(1);                                              \
    _Pragma("unroll")                                                           \
    for (int mi = 0; mi < 4; ++mi)                                              \
      _Pragma("unroll")                                                         \
      for (int ni = 0; ni < 2; ++ni) {                                          \
        const int am = ((Q) >= 2 ? 4 : 0) + mi;                                 \
        const int an = (((Q) == 1 || (Q) == 2) ? 2 : 0) + ni;                   \
        acc[am][an] = __builtin_amdgcn_mfma_f32_16x16x32_bf16(af[mi][0], bfr[ni][0], acc[am][an], 0, 0, 0); \
        acc[am][an] = __builtin_amdgcn_mfma_f32_16x16x32_bf16(af[mi][1], bfr[ni][1], acc[am][an], 0, 0, 0); \
      }                                                                         \
    __builtin_amdgcn_s_setprio(0);                                              \
  }

template<bool RELU, bool TOPK>
__global__ __launch_bounds__(512, 2) void k_mgemm8(
    const unsigned short* __restrict__ A,
    const unsigned short* __restrict__ BT,
    const float* __restrict__ bias,
    void* __restrict__ Cv, int M, int N, int K)
{
    // 132 KiB shared: staging buffers (128 KiB) alias the TOPK transpose buffer.
    __shared__ __align__(16) char SMEM[256*132*4];
    unsigned short* LAp = (unsigned short*)SMEM;        // 2 bufs x 16384 ushort
    unsigned short* LBp = LAp + 32768;                  // 2 bufs x 16384 ushort
    int t = threadIdx.x;

    // T1: XCD-aware swizzle of the flat block id (guarded for nwg % 8 != 0)
    int nwg = gridDim.x * gridDim.y;
    int bid = blockIdx.y * gridDim.x + blockIdx.x;
    int wgid = (nwg & 7) ? bid : ((bid & 7) * (nwg >> 3) + (bid >> 3));
    int ntm = M >> 8;
    int tm = wgid % ntm, tn = wgid / ntm;
    int m0 = tm << 8, n0 = tn << 8;

    int w = t >> 6, l = t & 63;
    int wm = w & 1, wn = w >> 1;
    int lr = l & 15, lq = l >> 4;

    const unsigned short* Abase = A  + (size_t)m0 * K;
    const unsigned short* Bbase = BT + (size_t)n0 * K;
    int NT = K >> 6;                 // K-tiles (requires NT >= 2)

    // precomputed stage offsets (per-thread constants)
    size_t ssrc0, ssrc1; int sdst0, sdst1;
    {
        int o0 = t * 16;
        int s0 = o0 ^ (((o0 >> 7) & 7) << 4);
        ssrc0 = (size_t)(s0 >> 7)*K + ((s0 & 127) >> 1);
        sdst0 = o0 >> 1;
        int o1 = (512 + t) * 16;
        int s1 = o1 ^ (((o1 >> 7) & 7) << 4);
        ssrc1 = (size_t)(s1 >> 7)*K + ((s1 & 127) >> 1);
        sdst1 = o1 >> 1;
    }

    // swizzled ds_read byte offsets (per-thread constants)
    int aoff[4][2], boff[2][2];
    #pragma unroll
    for (int mi = 0; mi < 4; ++mi)
        #pragma unroll
        for (int kq = 0; kq < 2; ++kq) {
            int lo = (wm*64 + mi*16 + lr)*128 + kq*64 + lq*16;
            aoff[mi][kq] = lo ^ (((lo >> 7) & 7) << 4);
        }
    #pragma unroll
    for (int ni = 0; ni < 2; ++ni)
        #pragma unroll
        for (int kq = 0; kq < 2; ++kq) {
            int lo = (wn*32 + ni*16 + lr)*128 + kq*64 + lq*16;
            boff[ni][kq] = lo ^ (((lo >> 7) & 7) << 4);
        }

    f32x4 acc[8][4];
    #pragma unroll
    for (int i = 0; i < 8; ++i)
        #pragma unroll
        for (int j = 0; j < 4; ++j)
            #pragma unroll
            for (int r = 0; r < 4; ++r) acc[i][j][r] = 0.f;

    bf16x8 af[4][2], bfr[2][2];

    // prologue: K-tile 0 into buf 0, need-order [A0,B0,B1,A1] (8 loads);
    // vmcnt(4) lands A0+B0 (phase 0's reads), barrier publishes.
    STG(Abase,                  LAp);
    STG(Bbase,                  LBp);
    STG(Bbase + (size_t)128*K,  LBp + 8192);
    STG(Abase + (size_t)128*K,  LAp + 8192);
    asm volatile("s_waitcnt vmcnt(4)" ::: "memory");
    __builtin_amdgcn_s_barrier();
    asm volatile("" ::: "memory");

    for (int kt = 0; kt < NT - 1; ++kt) {
        const unsigned short* la = LAp + (kt & 1)*16384;
        const unsigned short* lb = LBp + (kt & 1)*16384;
        unsigned short* nla = LAp + ((kt + 1) & 1)*16384;
        unsigned short* nlb = LBp + ((kt + 1) & 1)*16384;
        const unsigned short* An = Abase + (size_t)((kt + 1) << 6);
        const unsigned short* Bn = Bbase + (size_t)((kt + 1) << 6);
        MM8_PHASE(0, la, lb, STG(An, nla), 4);
        MM8_PHASE(1, la, lb, STG(Bn, nlb), 4);
        MM8_PHASE(2, la, lb, STG(Bn + (size_t)128*K, nlb + 8192), 4);
        MM8_PHASE(3, la, lb, STG(An + (size_t)128*K, nla + 8192), 4);
    }
    {   // last K-tile: drain 2 -> 0
        const unsigned short* la = LAp + ((NT - 1) & 1)*16384;
        const unsigned short* lb = LBp + ((NT - 1) & 1)*16384;
        MM8_PHASE(0, la, lb, (void)0, 2);
        MM8_PHASE(1, la, lb, (void)0, 0);
        MM8_PHASE(2, la, lb, (void)0, 0);
        MM8_PHASE(3, la, lb, (void)0, 0);
    }

    if (!TOPK) {
        // epilogue: acc[mi][ni] -> rows (mi&4 ? 128:0)+wm*64+(mi&3)*16+lq*4+r,
        //                          cols (ni&2 ? 128:0)+wn*32+(ni&1)*16+lr
        unsigned short* C = (unsigned short*)Cv;
        #pragma unroll
        for (int mi = 0; mi < 8; ++mi) {
            int grow = m0 + ((mi & 4) ? 128 : 0) + wm*64 + (mi & 3)*16 + lq*4;
            #pragma unroll
            for (int ni = 0; ni < 4; ++ni) {
                int gcol = n0 + ((ni & 2) ? 128 : 0) + wn*32 + (ni & 1)*16 + lr;
                float bv = bias[gcol];
                #pragma unroll
                for (int r = 0; r < 4; ++r) {
                    float v = acc[mi][ni][r] + bv;
                    if (RELU) v = relu_(v);
                    C[(size_t)(grow + r)*N + gcol] = f2b(v);
                }
            }
        }
    } else {
        // fused top-18-sum/8 v4: [row][stride 257] layout, 2 lanes/bank on scan
        // reads / publish / merge.
        float* TP = (float*)SMEM;           // [128 row][stride 257] f32, 131.6 KB
        float* redp = (float*)Cv;           // chunk-local red base
        int colId = t & 255;
        int half  = t >> 8;                 // 0: rows 0-63, 1: rows 64-127
        #pragma unroll
        for (int h = 0; h < 2; ++h) {
            __syncthreads();                // prior LDS use retired
            #pragma unroll
            for (int mi4 = 0; mi4 < 4; ++mi4) {
                int j0 = wm*64 + mi4*16 + lq*4;
                #pragma unroll
                for (int ni = 0; ni < 4; ++ni) {
                    int colLocal = ((ni & 2) ? 128 : 0) + wn*32 + (ni & 1)*16 + lr;
                    float bv = bias[n0 + colLocal];
                    #pragma unroll
                    for (int r = 0; r < 4; ++r)
                        TP[(j0 + r)*257 + colLocal] = acc[h*4 + mi4][ni][r] + bv;
                }
            }
            __syncthreads();
            // 64-element scan: batched loads + paired dep-free insertion
            float sm[TOPKN];
            #pragma unroll
            for (int x = 0; x < TOPKN; ++x) sm[x] = -INFINITY;
            const float* base = TP + (half*64)*257 + colId;
            for (int jb = 0; jb < 64; jb += 8) {
                float v[8];
                #pragma unroll
                for (int i = 0; i < 8; ++i) v[i] = base[(jb + i)*257];
                #pragma unroll
                for (int p = 0; p < 4; ++p) {
                    float hi = fmaxf(v[2*p], v[2*p+1]);
                    float lo = fminf(v[2*p], v[2*p+1]);
                    #pragma unroll
                    for (int x = TOPKN-1; x >= 2; --x)
                        sm[x] = fmaxf(fmaxf(sm[x], fminf(sm[x-1], hi)),
                                      fminf(sm[x-2], lo));
                    sm[1] = fmaxf(fmaxf(sm[1], fminf(sm[0], hi)), lo);
                    sm[0] = fmaxf(sm[0], hi);
                }
            }
            __syncthreads();
            if (half) {                     // publish upper half's sorted-18
                #pragma unroll
                for (int x = 0; x < TOPKN; ++x) TP[x*257 + colId] = sm[x];
            }
            __syncthreads();
            if (!half) {
                float B[TOPKN];
                #pragma unroll
                for (int x = 0; x < TOPKN; ++x) B[x] = TP[x*257 + colId];
                float s = 0.f;
                #pragma unroll
                for (int k = 0; k < TOPKN; ++k) {
                    float m = fmaxf(sm[k], B[k]);
                    #pragma unroll
                    for (int i = 1; i <= k; ++i)
                        m = fmaxf(m, fminf(sm[i-1], B[k-i]));
                    s += m;
                }
                redp[(size_t)((m0 >> 7) + h)*N + n0 + colId] = s * 0.125f;
            }
        }
    }
}

// -------- h1 via MFMA (K=64, single iteration): relu(geo@W1c + U + V + b1) --------
// ROUND-14: swapped-operand MFMA (mfma(bf, af)) transposes the output fragment:
// each lane's 4 regs now hold 4 CONSECUTIVE COLUMNS (n = lq*4+r) at one row
// (m = lr). Epilogue does ushort4 U loads + ushort4 h1c stores (4x fewer memory
// instructions) with NO LDS and NO occupancy change (round-12's 66 KB LDS
// transpose dropped 5 -> 2 blocks/CU and cost +48 us; this is the register-level
// alternative). Layout per m89: C col=lane&15 -> B-operand free dim (= af rows
// = our m), C row=(lane>>4)*4+r -> A-operand free dim (= bf rows = our n).
__global__ __launch_bounds__(256) void k_h1m(
    const unsigned short* __restrict__ A,
    const unsigned short* __restrict__ BT,
    const float* __restrict__ b1,
    const unsigned short* __restrict__ U, const unsigned short* __restrict__ V,
    unsigned short* __restrict__ h1c, int pofs)
{
    __shared__ unsigned short As[2*128*32];
    __shared__ unsigned short Bs[2*128*32];
    const int K = GEO;   // 64
    int t  = threadIdx.x;
    int m0 = blockIdx.x * 128;
    int n0 = blockIdx.y * 128;
    int w  = t >> 6, l = t & 63;
    int wm = w & 1, wn = w >> 1;
    int lr = l & 15;
    int lq = l >> 4;

    int s0 = w*2, s1 = w*2 + 1;
    int srow = l >> 2;
    int sko  = (l & 3) * 8;
    int rowA0 = s0*16 + srow, rowA1 = s1*16 + srow;

    f32x4 acc[4][4];
    #pragma unroll
    for (int mi = 0; mi < 4; ++mi)
        #pragma unroll
        for (int ni = 0; ni < 4; ++ni)
            #pragma unroll
            for (int r = 0; r < 4; ++r) acc[mi][ni][r] = 0.f;

    #pragma unroll
    for (int q = 0; q < 2; ++q) {
        int kg = q*32 + sko;
        glds16(A  + (size_t)(m0 + rowA0)*K + kg, As + q*4096 + s0*512 + l*8);
        glds16(A  + (size_t)(m0 + rowA1)*K + kg, As + q*4096 + s1*512 + l*8);
        glds16(BT + (size_t)(n0 + rowA0)*K + kg, Bs + q*4096 + s0*512 + l*8);
        glds16(BT + (size_t)(n0 + rowA1)*K + kg, Bs + q*4096 + s1*512 + l*8);
    }
    __syncthreads();
    #pragma unroll
    for (int q = 0; q < 2; ++q) {
        bf16x8 af[4], bf[4];
        #pragma unroll
        for (int mi = 0; mi < 4; ++mi)
            af[mi] = *(const bf16x8*)(As + q*4096 + (wm*64 + mi*16 + lr)*32 + lq*8);
        #pragma unroll
        for (int ni = 0; ni < 4; ++ni)
            bf[ni] = *(const bf16x8*)(Bs + q*4096 + (wn*64 + ni*16 + lr)*32 + lq*8);
        #pragma unroll
        for (int mi = 0; mi < 4; ++mi)
            #pragma unroll
            for (int ni = 0; ni < 4; ++ni)
                acc[mi][ni] = __builtin_amdgcn_mfma_f32_16x16x32_bf16(bf[ni], af[mi], acc[mi][ni], 0, 0, 0);
    }

    // epilogue (swapped layout): acc[mi][ni][r] = C[m][n] with
    //   m = wm*64 + mi*16 + lr,  n = wn*64 + ni*16 + lq*4 + r
    int p0 = pofs + m0;
    int bi = p0 >> 7;            // b*NP + i
    int b  = bi >> 7;
    const unsigned short* Ubase = U + (size_t)b*NP*D;
    const unsigned short* Vrow  = V + (size_t)bi*D;
    #pragma unroll
    for (int ni = 0; ni < 4; ++ni) {
        int gc = n0 + wn*64 + ni*16 + lq*4;
        ushort4 v4 = *(const ushort4*)(Vrow + gc);
        float4  b4 = *(const float4*)(b1 + gc);
        float add0 = b2f(v4.x) + b4.x;
        float add1 = b2f(v4.y) + b4.y;
        float add2 = b2f(v4.z) + b4.z;
        float add3 = b2f(v4.w) + b4.w;
        #pragma unroll
        for (int mi = 0; mi < 4; ++mi) {
            int row = wm*64 + mi*16 + lr;
            ushort4 u4 = *(const ushort4*)(Ubase + (size_t)row*D + gc);
            ushort4 o;
            o.x = f2b(relu_(acc[mi][ni][0] + b2f(u4.x) + add0));
            o.y = f2b(relu_(acc[mi][ni][1] + b2f(u4.y) + add1));
            o.z = f2b(relu_(acc[mi][ni][2] + b2f(u4.z) + add2));
            o.w = f2b(relu_(acc[mi][ni][3] + b2f(u4.w) + add3));
            *(ushort4*)(h1c + (size_t)(m0 + row)*D + gc) = o;
        }
    }
}

// ---------------- final heads -> sigmoid, f32 out ----------------
__global__ __launch_bounds__(256) void k_final(const float* __restrict__ x,
    const float* __restrict__ subject, const float* __restrict__ obj,
    const float* __restrict__ cs_w, const float* __restrict__ cs_b,
    const float* __restrict__ cso_w, const float* __restrict__ cso_b,
    float* __restrict__ out)
{
    int bi = blockIdx.x;
    int b  = bi >> 7;
    const float* xr = x + (size_t)bi*D;
    const float* sb = subject + (size_t)b*D;
    const float* ob = obj + (size_t)b*D;
    int tid = threadIdx.x;
    float a0 = 0.f, a1 = 0.f;
    for (int k = tid; k < D; k += 256) {
        float xv = xr[k];
        a0 = fmaf(xv, cs_w[k], a0);
        a0 = fmaf(sb[k], cs_w[D+k], a0);
        a1 = fmaf(xv, cso_w[k], a1);
        a1 = fmaf(ob[k], cso_w[D+k], a1);
    }
    __shared__ float r0[256], r1[256];
    r0[tid] = a0; r1[tid] = a1;
    __syncthreads();
    for (int s2 = 128; s2 > 0; s2 >>= 1) {
        if (tid < s2) { r0[tid] += r0[tid+s2]; r1[tid] += r1[tid+s2]; }
        __syncthreads();
    }
    if (tid == 0) {
        out[bi*2+0] = 1.f/(1.f + expf(-(r0[0] + cs_b[0])));
        out[bi*2+1] = 1.f/(1.f + expf(-(r1[0] + cso_b[0])));
    }
}

extern "C" void kernel_launch(void* const* d_in, const int* in_sizes, int n_in,
                              void* d_out, int out_size, void* d_ws, size_t ws_size,
                              hipStream_t stream)
{
    const float* feats   = (const float*)d_in[0];
    const float* subject = (const float*)d_in[1];
    const float* obj     = (const float*)d_in[2];
    const float* prop    = (const float*)d_in[3];
    const float* gp_w1 = (const float*)d_in[4];  const float* gp_b1 = (const float*)d_in[5];
    const float* gp_w2 = (const float*)d_in[6];  const float* gp_b2 = (const float*)d_in[7];
    const float* gp_w3 = (const float*)d_in[8];  const float* gp_b3 = (const float*)d_in[9];
    const float* pm_w1 = (const float*)d_in[10]; const float* pm_b1 = (const float*)d_in[11];
    const float* pm_w2 = (const float*)d_in[12]; const float* pm_b2 = (const float*)d_in[13];
    const float* pm_w3 = (const float*)d_in[14]; const float* pm_b3 = (const float*)d_in[15];
    const float* ag_w1 = (const float*)d_in[16]; const float* ag_b1 = (const float*)d_in[17];
    const float* ag_w2 = (const float*)d_in[18]; const float* ag_b2 = (const float*)d_in[19];
    const float* ag_w3 = (const float*)d_in[20]; const float* ag_b3 = (const float*)d_in[21];
    const float* cs_w  = (const float*)d_in[22]; const float* cs_b  = (const float*)d_in[23];
    const float* cso_w = (const float*)d_in[24]; const float* cso_b = (const float*)d_in[25];
    float* out = (float*)d_out;

    const int M = BS*NP;          // 256
    const int MN = M*D;           // 262144

    // ---- workspace layout (bytes). Cp aliases the chunk region ----
    char* wsb = (char*)d_ws;
    size_t off = 0;
    auto alloc = [&](size_t bytes) { char* p = wsb + off; off += (bytes + 255) & ~255ull; return p; };
    unsigned short* Ub = (unsigned short*)alloc((size_t)MN*2);
    unsigned short* Vb = (unsigned short*)alloc((size_t)MN*2);
    float* red = (float*)alloc((size_t)MN*4);
    float* xf  = (float*)alloc((size_t)MN*4);
    unsigned short* xh1b = (unsigned short*)alloc((size_t)MN*2);
    unsigned short* xh2b = (unsigned short*)alloc((size_t)MN*2);
    unsigned short* w1aT = (unsigned short*)alloc((size_t)D*D*2);
    unsigned short* w1bT = (unsigned short*)alloc((size_t)D*D*2);
    unsigned short* w1cT = (unsigned short*)alloc((size_t)D*GEO*2);
    unsigned short* w2T  = (unsigned short*)alloc((size_t)D*D*2);
    unsigned short* w3T  = (unsigned short*)alloc((size_t)D*D*2);
    unsigned short* agw1T= (unsigned short*)alloc((size_t)2*D*D*2);
    unsigned short* agw2T= (unsigned short*)alloc((size_t)D*D*2);
    unsigned short* agw3T= (unsigned short*)alloc((size_t)D*D*2);
    size_t persist = off;

    // shared region: Cp (split-K partials, phases 1&3) ALIASES chunk bufs (phase 2)
    size_t cp_bytes = (size_t)8*MN*4;                              // 8.4 MB
    size_t chunk_unit = (size_t)NP*(GEO*2 + D*2 + D*2);            // geo,h1,h2
    int CH = M;  // try the whole problem in one chunk
    while (CH > 2) {
        size_t region = (size_t)CH*chunk_unit;
        if (region < cp_bytes) region = cp_bytes;
        if (persist + region + 4096 <= ws_size) break;
        CH >>= 1;
    }
    float*          Cp    = (float*)(wsb + persist);
    unsigned short* geoPc = (unsigned short*)(wsb + persist);
    unsigned short* h1c   = geoPc + (size_t)CH*NP*GEO;
    unsigned short* h2c   = h1c   + (size_t)CH*NP*D;

    // 0) all weight transposes + bf16 in one dispatch (incl. W1c geo slice)
    WT8 d;
    d.src[0]=pm_w1;                d.dst[0]=w1aT;  d.kt[0]=16;
    d.src[1]=pm_w1+(size_t)D*D;    d.dst[1]=w1bT;  d.kt[1]=16;
    d.src[2]=pm_w1+(size_t)2*D*D;  d.dst[2]=w1cT;  d.kt[2]=1;
    d.src[3]=pm_w2;                d.dst[3]=w2T;   d.kt[3]=16;
    d.src[4]=pm_w3;                d.dst[4]=w3T;   d.kt[4]=16;
    d.src[5]=ag_w1;                d.dst[5]=agw1T; d.kt[5]=32;
    d.src[6]=ag_w2;                d.dst[6]=agw2T; d.kt[6]=16;
    d.src[7]=ag_w3;                d.dst[7]=agw3T; d.kt[7]=16;
    d.pre[0]=0;
    for (int e = 0; e < 8; ++e) d.pre[e+1] = d.pre[e] + d.kt[e]*16;
    k_wTall<<<d.pre[8], 256, 0, stream>>>(d);

    // 1) U,V = feats @ {w1a, w1b}: split-K MFMA (KZ=4, 2 mats) + reduce (bf16 out)
    k_skmm<true><<<dim3(M/16, D/128, 8), 256, 0, stream>>>(
        feats, nullptr, D, 0, w1aT, w1bT, Cp, 4, 256, D);
    k_red<false,true><<<dim3(MN/1024, 1, 2), 256, 0, stream>>>(
        Cp, 4, nullptr, Ub, Vb, MN, D);

    // 2) chunked over (b,i) rows: geo(MFMA) -> h1(MFMA) -> h2 -> fc+topk fused
    int nchunks = M/CH;
    for (int cchunk = 0; cchunk < nchunks; ++cchunk) {
        int bi0  = cchunk * CH;
        int pofs = bi0 * NP;
        k_geo2<<<CH*NP/256, 256, 0, stream>>>(prop, gp_w1, gp_b1, gp_w2, gp_b2, gp_w3, gp_b3, geoPc, pofs);
        dim3 gBig(CH*NP/128, D/128);
        k_h1m<<<gBig, 256, 0, stream>>>(geoPc, w1cT, pm_b1, Ub, Vb, h1c, pofs);
        dim3 g8(CH*NP/256, D/256);
        k_mgemm8<true ,false><<<g8, 512, 0, stream>>>(h1c, w2T, pm_b2, h2c, CH*NP, D, D);
        k_mgemm8<false,true ><<<g8, 512, 0, stream>>>(h2c, w3T, pm_b3, red + (size_t)bi0*D, CH*NP, D, D);
    }

    // 3) aggregate MLP via split-K MFMA + fused reduce/activation
    k_skmm<true><<<dim3(M/16, D/128, 8), 256, 0, stream>>>(
        feats, red, D, D, agw1T, nullptr, Cp, 8, 256, D);
    k_red<true,true><<<dim3(MN/1024, 1, 1), 256, 0, stream>>>(
        Cp, 8, ag_b1, xh1b, nullptr, MN, D);
    k_skmm<false><<<dim3(M/16, D/128, 4), 256, 0, stream>>>(
        xh1b, nullptr, D, 0, agw2T, nullptr, Cp, 4, 256, D);
    k_red<true,true><<<dim3(MN/1024, 1, 1), 256, 0, stream>>>(
        Cp, 4, ag_b2, xh2b, nullptr, MN, D);
    k_skmm<false><<<dim3(M/16, D/128, 4), 256, 0, stream>>>(
        xh2b, nullptr, D, 0, agw3T, nullptr, Cp, 4, 256, D);
    k_red<false,false><<<dim3(MN/1024, 1, 1), 256, 0, stream>>>(
        Cp, 4, ag_b3, xf, nullptr, MN, D);

    // 4) sigmoid heads
    k_final<<<M, 256, 0, stream>>>(xf, subject, obj, cs_w, cs_b, cso_w, cso_b, out);
}

// Round 15
// 407.468 us; speedup vs baseline: 1.0510x; 1.0510x over previous
//
#include <hip/hip_runtime.h>
#include <hip/hip_bf16.h>
#include <math.h>

#define D 1024
#define NP 128
#define BS 2
#define GEO 64
#define TOPKN 18
#define NPAIR (BS*NP*NP)   // 32768

__device__ __forceinline__ float relu_(float x){ return fmaxf(x, 0.f); }
__device__ __forceinline__ unsigned short f2b(float x){
    __hip_bfloat16 h = __float2bfloat16(x);
    return *(unsigned short*)&h;
}
__device__ __forceinline__ float b2f(unsigned short u){
    return __uint_as_float((unsigned)u << 16);
}

typedef short bf16x8 __attribute__((ext_vector_type(8)));
typedef float f32x4  __attribute__((ext_vector_type(4)));

// async global->LDS, 16B per lane. LDS dest must be wave-uniform base + lane*16.
__device__ __forceinline__ void glds16(const unsigned short* g, unsigned short* l){
    __builtin_amdgcn_global_load_lds(
        (const __attribute__((address_space(1))) void*)g,
        (__attribute__((address_space(3))) void*)l,
        16, 0, 0);
}

// ------- geo embedding + 3x Linear(64,64) via MFMA (chunk-local, bf16 out) -------
#define GSTR 72
__global__ __launch_bounds__(256) void k_geo2(
    const float* __restrict__ prop,
    const float* __restrict__ gw1, const float* __restrict__ gb1,
    const float* __restrict__ gw2, const float* __restrict__ gb2,
    const float* __restrict__ gw3, const float* __restrict__ gb3,
    unsigned short* __restrict__ geoPc, int pofs)
{
    __shared__ unsigned short WT[3][GEO*GSTR];   // W^T bf16, padded: 27.6 KB
    __shared__ float gb[3][GEO];
    __shared__ unsigned short buf[4][GEO*GSTR];  // per-wave act tile: 36.9 KB
    int t = threadIdx.x, l = t & 63, w = t >> 6;

    for (int idx = t; idx < GEO*GEO; idx += 256) {
        int k = idx >> 6, n = idx & 63;          // W[k][n], coalesced over n
        WT[0][n*GSTR + k] = f2b(gw1[idx]);
        WT[1][n*GSTR + k] = f2b(gw2[idx]);
        WT[2][n*GSTR + k] = f2b(gw3[idx]);
    }
    if (t < GEO) { gb[0][t]=gb1[t]; gb[1][t]=gb2[t]; gb[2][t]=gb3[t]; }

    int plocal = blockIdx.x*256 + w*64;          // chunk-local pair base
    int pair0  = pofs + plocal;                  // global pair base
    int c = l;
    int p = c >> 4, s = c & 15, f = s & 7;
    float dm = expf((float)f * (6.907755278982137f/8.0f)); // 1000^(f/8)
    bool is_cos = (s & 8) != 0;
    float scale = 100.f / dm;

    int b  = pair0 >> 14;
    int ij = pair0 & 16383;
    int i  = ij >> 7;
    int j0 = ij & 127;
    float4 pi = *(const float4*)(prop + (size_t)(b*NP + i)*4);
    float wi  = pi.z-pi.x+1.f, hi_ = pi.w-pi.y+1.f;
    unsigned short* mybuf = buf[w];
    for (int r = 0; r < 64; ++r) {
        float4 pj = *(const float4*)(prop + (size_t)(b*NP + j0 + r)*4);
        float wj  = pj.z-pj.x+1.f, hj  = pj.w-pj.y+1.f;
        float pos;
        if      (p == 0) pos = (0.5f*(pi.x+pi.z) - 0.5f*(pj.x+pj.z)) / wj;
        else if (p == 1) pos = (0.5f*(pi.y+pi.w) - 0.5f*(pj.y+pj.w)) / hj;
        else if (p == 2) pos = wi / wj;
        else             pos = hi_ / hj;
        pos = logf(fmaxf(fabsf(pos), 1e-3f));
        float dv = pos * scale;
        mybuf[r*GSTR + c] = f2b(is_cos ? cosf(dv) : sinf(dv));
    }
    __syncthreads();

    int lr = l & 15, lq = l >> 4;
    #pragma unroll
    for (int layer = 0; layer < 3; ++layer) {
        const unsigned short* WTl = WT[layer];
        f32x4 acc[4][4];
        #pragma unroll
        for (int mi = 0; mi < 4; ++mi)
            #pragma unroll
            for (int ni = 0; ni < 4; ++ni)
                #pragma unroll
                for (int r = 0; r < 4; ++r) acc[mi][ni][r] = 0.f;
        #pragma unroll
        for (int kc = 0; kc < 2; ++kc) {
            bf16x8 af[4], bf[4];
            #pragma unroll
            for (int mi = 0; mi < 4; ++mi)
                af[mi] = *(const bf16x8*)(mybuf + (mi*16+lr)*GSTR + kc*32 + lq*8);
            #pragma unroll
            for (int ni = 0; ni < 4; ++ni)
                bf[ni] = *(const bf16x8*)(WTl + (ni*16+lr)*GSTR + kc*32 + lq*8);
            #pragma unroll
            for (int mi = 0; mi < 4; ++mi)
                #pragma unroll
                for (int ni = 0; ni < 4; ++ni)
                    acc[mi][ni] = __builtin_amdgcn_mfma_f32_16x16x32_bf16(af[mi], bf[ni], acc[mi][ni], 0, 0, 0);
        }
        __syncthreads();
        #pragma unroll
        for (int mi = 0; mi < 4; ++mi) {
            #pragma unroll
            for (int ni = 0; ni < 4; ++ni) {
                int col = ni*16 + lr;
                float bv = gb[layer][col];
                #pragma unroll
                for (int r = 0; r < 4; ++r) {
                    int row = mi*16 + lq*4 + r;
                    float v = acc[mi][ni][r] + bv;
                    if (layer < 2) {
                        mybuf[row*GSTR + col] = f2b(relu_(v));
                    } else {
                        geoPc[(size_t)(plocal + row)*GEO + col] = f2b(v);
                    }
                }
            }
        }
        __syncthreads();
    }
}

// ------------- batched weight transpose+bf16: 8 matrices, N=1024 cols -------------
struct WT8 {
    const float* src[8];
    unsigned short* dst[8];
    int kt[8];     // K/64
    int pre[9];    // prefix of tile counts (kt*16)
};
__global__ __launch_bounds__(256) void k_wTall(WT8 d)
{
    __shared__ float tile[64][65];
    int bid = blockIdx.x;
    int e = 0;
    while (e < 7 && bid >= d.pre[e+1]) ++e;
    int local = bid - d.pre[e];
    int bx = local & 15;      // n-tile (N=1024 -> 16 tiles)
    int by = local >> 4;      // k-tile
    int K = d.kt[e] * 64;
    const float* W = d.src[e];
    unsigned short* WT = d.dst[e];
    int t = threadIdx.x;
    int tc = t & 63, tr = t >> 6;
    #pragma unroll
    for (int r = tr; r < 64; r += 4)
        tile[r][tc] = W[(size_t)(by*64 + r)*1024 + bx*64 + tc];
    __syncthreads();
    #pragma unroll
    for (int r = tr; r < 64; r += 4)
        WT[(size_t)(bx*64 + r)*K + by*64 + tc] = f2b(tile[tc][r]);
}

// ---------------- split-K MFMA GEMM for M=256 layers ----------------
// NOTE (round 7 lesson): do NOT replace these split-K pairs with direct full-K
// kernels. Direct kernels launch <=256 blocks (<=1/CU, half-idle GPU) and expose
// global-load latency every K-step; measured +50 us total. Split-K's 512-1024
// blocks provide the in-kernel TLP that hides latency; launch gaps are small.
template<bool A_F32>
__global__ __launch_bounds__(256) void k_skmm(
    const void* __restrict__ A1v, const void* __restrict__ A2v,
    int K1, int K2,
    const unsigned short* __restrict__ BT0,
    const unsigned short* __restrict__ BT1,
    float* __restrict__ Cp,
    int KZ, int Kc, int N)
{
    __shared__ unsigned short As[16*32];
    __shared__ unsigned short Bs[128*32];
    int t = threadIdx.x;
    int m0 = blockIdx.x * 16;
    int n0 = blockIdx.y * 128;
    int bz = blockIdx.z;
    int kz = bz % KZ;
    int mat = bz / KZ;
    const unsigned short* BT = mat ? BT1 : BT0;
    int K = K1 + K2;
    int M = gridDim.x * 16;
    int w = t >> 6, l = t & 63;
    int lr = l & 15, lq = l >> 4;
    int arow = t >> 3, ak = (t & 7) * 4;
    int arow2 = t >> 2, ak2 = (t & 3) * 8;
    int brow = t >> 1, bk = (t & 1) * 16;
    f32x4 acc0 = {0.f,0.f,0.f,0.f}, acc1 = {0.f,0.f,0.f,0.f};
    for (int i = 0; i < Kc; i += 32) {
        int kg0 = kz*Kc + i;
        __syncthreads();
        if (A_F32) {
            if (t < 128) {
                int kg = kg0 + ak;
                const float* src = (kg < K1)
                    ? (const float*)A1v + (size_t)(m0+arow)*K1 + kg
                    : (const float*)A2v + (size_t)(m0+arow)*K2 + (kg - K1);
                float4 a4 = *(const float4*)src;
                ushort4 u;
                u.x=f2b(a4.x); u.y=f2b(a4.y); u.z=f2b(a4.z); u.w=f2b(a4.w);
                *(ushort4*)(As + arow*32 + ak) = u;
            }
        } else {
            if (t < 64) {
                const unsigned short* src = (const unsigned short*)A1v + (size_t)(m0+arow2)*K1 + kg0 + ak2;
                *(bf16x8*)(As + arow2*32 + ak2) = *(const bf16x8*)src;
            }
        }
        const unsigned short* srcb = BT + (size_t)(n0+brow)*K + kg0 + bk;
        *(bf16x8*)(Bs + brow*32 + bk)     = *(const bf16x8*)srcb;
        *(bf16x8*)(Bs + brow*32 + bk + 8) = *(const bf16x8*)(srcb + 8);
        __syncthreads();
        bf16x8 af = *(const bf16x8*)(As + lr*32 + lq*8);
        bf16x8 b0 = *(const bf16x8*)(Bs + (w*32      + lr)*32 + lq*8);
        bf16x8 b1 = *(const bf16x8*)(Bs + (w*32 + 16 + lr)*32 + lq*8);
        acc0 = __builtin_amdgcn_mfma_f32_16x16x32_bf16(af, b0, acc0, 0, 0, 0);
        acc1 = __builtin_amdgcn_mfma_f32_16x16x32_bf16(af, b1, acc1, 0, 0, 0);
    }
    float* Co = Cp + (size_t)bz*M*N;
    #pragma unroll
    for (int r = 0; r < 4; ++r) {
        int gr = m0 + lq*4 + r;
        Co[(size_t)gr*N + n0 + w*32      + lr] = acc0[r];
        Co[(size_t)gr*N + n0 + w*32 + 16 + lr] = acc1[r];
    }
}

// ---------------- reduce split-K partials: out = act(sum + bias) ----------------
template<bool RELU, bool OUT_BF16>
__global__ __launch_bounds__(256) void k_red(
    const float* __restrict__ Cp, int KZ,
    const float* __restrict__ bias,
    void* __restrict__ out0, void* __restrict__ out1,
    int MN, int N)
{
    int z = blockIdx.z;
    const float* C = Cp + (size_t)z*KZ*MN;
    void* out = z ? out1 : out0;
    int idx = (blockIdx.x*256 + threadIdx.x) * 4;
    f32x4 s = {0.f,0.f,0.f,0.f};
    for (int k = 0; k < KZ; ++k)
        s += *(const f32x4*)(C + (size_t)k*MN + idx);
    if (bias) s += *(const f32x4*)(bias + (idx & (N-1)));
    if (RELU) { s[0]=relu_(s[0]); s[1]=relu_(s[1]); s[2]=relu_(s[2]); s[3]=relu_(s[3]); }
    if (OUT_BF16) {
        ushort4 u; u.x=f2b(s[0]); u.y=f2b(s[1]); u.z=f2b(s[2]); u.w=f2b(s[3]);
        *(ushort4*)((unsigned short*)out + idx) = u;
    } else {
        float4 o; o.x=s[0]; o.y=s[1]; o.z=s[2]; o.w=s[3];
        *(float4*)((float*)out + idx) = o;
    }
}

// ===== 8-phase 256x256 bf16 MFMA GEMM (T1+T2+T3+T4+T5), C = act(A@B^T + bias) =====
// ROUND-4 SCHEDULE (measured best: ~78-80 us, MfmaUtil ~35.5, bank conflicts 0).
//
// TOPK epilogue v4 (round-12, measured 96.5 us vs v3's 114.8): layout
// TP[row 128][stride 257]; scan reads/publish/merge all land 2 lanes/bank.
// Scan = dep-free paired insertion; merge = static-index order-statistic.
//
// LDS swizzle (verified: conflicts 7.3M -> 0): phys = lo ^ ((row&7)<<4). Linear
// glds dest + inverse-swizzled global source + swizzled ds_read offsets (#21).

#define STG(g, lb) { glds16((g) + ssrc0, (lb) + sdst0); glds16((g) + ssrc1, (lb) + sdst1); }

#define MM8_PHASE(Q, LAH, LBH, STAGE_STMT, VM)                                  \
  {                                                                             \
    if ((Q) == 0 || (Q) == 2) {                                                 \
      const char* ah = (const char*)(LAH) + ((Q) == 2 ? 16384 : 0);             \
      _Pragma("unroll")                                                         \
      for (int mi = 0; mi < 4; ++mi) {                                          \
        af[mi][0] = *(const bf16x8*)(ah + aoff[mi][0]);                         \
        af[mi][1] = *(const bf16x8*)(ah + aoff[mi][1]);                         \
      }                                                                         \
    }                                                                           \
    if ((Q) != 2) {                                                             \
      const char* bh = (const char*)(LBH) + ((Q) == 1 ? 16384 : 0);             \
      _Pragma("unroll")                                                         \
      for (int ni = 0; ni < 2; ++ni) {                                          \
        bfr[ni][0] = *(const bf16x8*)(bh + boff[ni][0]);                        \
        bfr[ni][1] = *(const bf16x8*)(bh + boff[ni][1]);                        \
      }                                                                         \
    }                                                                           \
    STAGE_STMT;                                                                 \
    asm volatile("s_waitcnt vmcnt(" #VM ")" ::: "memory");                      \
    __builtin_amdgcn_s_barrier();                                               \
    asm volatile("" ::: "memory");                                              \
    __builtin_amdgcn_s_setprio(1);                                              \
    _Pragma("unroll")                                                           \
    for (int mi = 0; mi < 4; ++mi)                                              \
      _Pragma("unroll")                                                         \
      for (int ni = 0; ni < 2; ++ni) {                                          \
        const int am = ((Q) >= 2 ? 4 : 0) + mi;                                 \
        const int an = (((Q) == 1 || (Q) == 2) ? 2 : 0) + ni;                   \
        acc[am][an] = __builtin_amdgcn_mfma_f32_16x16x32_bf16(af[mi][0], bfr[ni][0], acc[am][an], 0, 0, 0); \
        acc[am][an] = __builtin_amdgcn_mfma_f32_16x16x32_bf16(af[mi][1], bfr[ni][1], acc[am][an], 0, 0, 0); \
      }                                                                         \
    __builtin_amdgcn_s_setprio(0);                                              \
  }

template<bool RELU, bool TOPK>
__global__ __launch_bounds__(512, 2) void k_mgemm8(
    const unsigned short* __restrict__ A,
    const unsigned short* __restrict__ BT,
    const float* __restrict__ bias,
    void* __restrict__ Cv, int M, int N, int K)
{
    // 132 KiB shared: staging buffers (128 KiB) alias the TOPK transpose buffer.
    __shared__ __align__(16) char SMEM[256*132*4];
    unsigned short* LAp = (unsigned short*)SMEM;        // 2 bufs x 16384 ushort
    unsigned short* LBp = LAp + 32768;                  // 2 bufs x 16384 ushort
    int t = threadIdx.x;

    // T1: XCD-aware swizzle of the flat block id (guarded for nwg % 8 != 0)
    int nwg = gridDim.x * gridDim.y;
    int bid = blockIdx.y * gridDim.x + blockIdx.x;
    int wgid = (nwg & 7) ? bid : ((bid & 7) * (nwg >> 3) + (bid >> 3));
    int ntm = M >> 8;
    int tm = wgid % ntm, tn = wgid / ntm;
    int m0 = tm << 8, n0 = tn << 8;

    int w = t >> 6, l = t & 63;
    int wm = w & 1, wn = w >> 1;
    int lr = l & 15, lq = l >> 4;

    const unsigned short* Abase = A  + (size_t)m0 * K;
    const unsigned short* Bbase = BT + (size_t)n0 * K;
    int NT = K >> 6;                 // K-tiles (requires NT >= 2)

    // precomputed stage offsets (per-thread constants)
    size_t ssrc0, ssrc1; int sdst0, sdst1;
    {
        int o0 = t * 16;
        int s0 = o0 ^ (((o0 >> 7) & 7) << 4);
        ssrc0 = (size_t)(s0 >> 7)*K + ((s0 & 127) >> 1);
        sdst0 = o0 >> 1;
        int o1 = (512 + t) * 16;
        int s1 = o1 ^ (((o1 >> 7) & 7) << 4);
        ssrc1 = (size_t)(s1 >> 7)*K + ((s1 & 127) >> 1);
        sdst1 = o1 >> 1;
    }

    // swizzled ds_read byte offsets (per-thread constants)
    int aoff[4][2], boff[2][2];
    #pragma unroll
    for (int mi = 0; mi < 4; ++mi)
        #pragma unroll
        for (int kq = 0; kq < 2; ++kq) {
            int lo = (wm*64 + mi*16 + lr)*128 + kq*64 + lq*16;
            aoff[mi][kq] = lo ^ (((lo >> 7) & 7) << 4);
        }
    #pragma unroll
    for (int ni = 0; ni < 2; ++ni)
        #pragma unroll
        for (int kq = 0; kq < 2; ++kq) {
            int lo = (wn*32 + ni*16 + lr)*128 + kq*64 + lq*16;
            boff[ni][kq] = lo ^ (((lo >> 7) & 7) << 4);
        }

    f32x4 acc[8][4];
    #pragma unroll
    for (int i = 0; i < 8; ++i)
        #pragma unroll
        for (int j = 0; j < 4; ++j)
            #pragma unroll
            for (int r = 0; r < 4; ++r) acc[i][j][r] = 0.f;

    bf16x8 af[4][2], bfr[2][2];

    // prologue: K-tile 0 into buf 0, need-order [A0,B0,B1,A1] (8 loads);
    // vmcnt(4) lands A0+B0 (phase 0's reads), barrier publishes.
    STG(Abase,                  LAp);
    STG(Bbase,                  LBp);
    STG(Bbase + (size_t)128*K,  LBp + 8192);
    STG(Abase + (size_t)128*K,  LAp + 8192);
    asm volatile("s_waitcnt vmcnt(4)" ::: "memory");
    __builtin_amdgcn_s_barrier();
    asm volatile("" ::: "memory");

    for (int kt = 0; kt < NT - 1; ++kt) {
        const unsigned short* la = LAp + (kt & 1)*16384;
        const unsigned short* lb = LBp + (kt & 1)*16384;
        unsigned short* nla = LAp + ((kt + 1) & 1)*16384;
        unsigned short* nlb = LBp + ((kt + 1) & 1)*16384;
        const unsigned short* An = Abase + (size_t)((kt + 1) << 6);
        const unsigned short* Bn = Bbase + (size_t)((kt + 1) << 6);
        MM8_PHASE(0, la, lb, STG(An, nla), 4);
        MM8_PHASE(1, la, lb, STG(Bn, nlb), 4);
        MM8_PHASE(2, la, lb, STG(Bn + (size_t)128*K, nlb + 8192), 4);
        MM8_PHASE(3, la, lb, STG(An + (size_t)128*K, nla + 8192), 4);
    }
    {   // last K-tile: drain 2 -> 0
        const unsigned short* la = LAp + ((NT - 1) & 1)*16384;
        const unsigned short* lb = LBp + ((NT - 1) & 1)*16384;
        MM8_PHASE(0, la, lb, (void)0, 2);
        MM8_PHASE(1, la, lb, (void)0, 0);
        MM8_PHASE(2, la, lb, (void)0, 0);
        MM8_PHASE(3, la, lb, (void)0, 0);
    }

    if (!TOPK) {
        // epilogue: acc[mi][ni] -> rows (mi&4 ? 128:0)+wm*64+(mi&3)*16+lq*4+r,
        //                          cols (ni&2 ? 128:0)+wn*32+(ni&1)*16+lr
        unsigned short* C = (unsigned short*)Cv;
        #pragma unroll
        for (int mi = 0; mi < 8; ++mi) {
            int grow = m0 + ((mi & 4) ? 128 : 0) + wm*64 + (mi & 3)*16 + lq*4;
            #pragma unroll
            for (int ni = 0; ni < 4; ++ni) {
                int gcol = n0 + ((ni & 2) ? 128 : 0) + wn*32 + (ni & 1)*16 + lr;
                float bv = bias[gcol];
                #pragma unroll
                for (int r = 0; r < 4; ++r) {
                    float v = acc[mi][ni][r] + bv;
                    if (RELU) v = relu_(v);
                    C[(size_t)(grow + r)*N + gcol] = f2b(v);
                }
            }
        }
    } else {
        // fused top-18-sum/8 v4: [row][stride 257] layout, 2 lanes/bank on scan
        // reads / publish / merge.
        float* TP = (float*)SMEM;           // [128 row][stride 257] f32, 131.6 KB
        float* redp = (float*)Cv;           // chunk-local red base
        int colId = t & 255;
        int half  = t >> 8;                 // 0: rows 0-63, 1: rows 64-127
        #pragma unroll
        for (int h = 0; h < 2; ++h) {
            __syncthreads();                // prior LDS use retired
            #pragma unroll
            for (int mi4 = 0; mi4 < 4; ++mi4) {
                int j0 = wm*64 + mi4*16 + lq*4;
                #pragma unroll
                for (int ni = 0; ni < 4; ++ni) {
                    int colLocal = ((ni & 2) ? 128 : 0) + wn*32 + (ni & 1)*16 + lr;
                    float bv = bias[n0 + colLocal];
                    #pragma unroll
                    for (int r = 0; r < 4; ++r)
                        TP[(j0 + r)*257 + colLocal] = acc[h*4 + mi4][ni][r] + bv;
                }
            }
            __syncthreads();
            // 64-element scan: batched loads + paired dep-free insertion
            float sm[TOPKN];
            #pragma unroll
            for (int x = 0; x < TOPKN; ++x) sm[x] = -INFINITY;
            const float* base = TP + (half*64)*257 + colId;
            for (int jb = 0; jb < 64; jb += 8) {
                float v[8];
                #pragma unroll
                for (int i = 0; i < 8; ++i) v[i] = base[(jb + i)*257];
                #pragma unroll
                for (int p = 0; p < 4; ++p) {
                    float hi = fmaxf(v[2*p], v[2*p+1]);
                    float lo = fminf(v[2*p], v[2*p+1]);
                    #pragma unroll
                    for (int x = TOPKN-1; x >= 2; --x)
                        sm[x] = fmaxf(fmaxf(sm[x], fminf(sm[x-1], hi)),
                                      fminf(sm[x-2], lo));
                    sm[1] = fmaxf(fmaxf(sm[1], fminf(sm[0], hi)), lo);
                    sm[0] = fmaxf(sm[0], hi);
                }
            }
            __syncthreads();
            if (half) {                     // publish upper half's sorted-18
                #pragma unroll
                for (int x = 0; x < TOPKN; ++x) TP[x*257 + colId] = sm[x];
            }
            __syncthreads();
            if (!half) {
                float B[TOPKN];
                #pragma unroll
                for (int x = 0; x < TOPKN; ++x) B[x] = TP[x*257 + colId];
                float s = 0.f;
                #pragma unroll
                for (int k = 0; k < TOPKN; ++k) {
                    float m = fmaxf(sm[k], B[k]);
                    #pragma unroll
                    for (int i = 1; i <= k; ++i)
                        m = fmaxf(m, fminf(sm[i-1], B[k-i]));
                    s += m;
                }
                redp[(size_t)((m0 >> 7) + h)*N + n0 + colId] = s * 0.125f;
            }
        }
    }
}

// -------- h1 via MFMA (K=64, single iteration): relu(geo@W1c + U + V + b1) --------
// ROUND-13 VERSION (measured best; part of the 409.0 us config).
// R12 lesson: 66 KB LDS transpose drops occupancy 5 -> 2 blocks/CU (+48 us).
// R14 lesson: swapped-operand MFMA puts adjacent LANES in different ROWS ->
// 64 isolated 8 B segments per store (coalescing is a wave property) (+19 us).
// Keep the scalar epilogue: 4x32 B contiguous segments per store instruction.
__global__ __launch_bounds__(256) void k_h1m(
    const unsigned short* __restrict__ A,
    const unsigned short* __restrict__ BT,
    const float* __restrict__ b1,
    const unsigned short* __restrict__ U, const unsigned short* __restrict__ V,
    unsigned short* __restrict__ h1c, int pofs)
{
    __shared__ unsigned short As[2*128*32];
    __shared__ unsigned short Bs[2*128*32];
    const int K = GEO;   // 64
    int t  = threadIdx.x;
    int m0 = blockIdx.x * 128;
    int n0 = blockIdx.y * 128;
    int w  = t >> 6, l = t & 63;
    int wm = w & 1, wn = w >> 1;
    int lr = l & 15;
    int lq = l >> 4;

    int s0 = w*2, s1 = w*2 + 1;
    int srow = l >> 2;
    int sko  = (l & 3) * 8;
    int rowA0 = s0*16 + srow, rowA1 = s1*16 + srow;

    f32x4 acc[4][4];
    #pragma unroll
    for (int mi = 0; mi < 4; ++mi)
        #pragma unroll
        for (int ni = 0; ni < 4; ++ni)
            #pragma unroll
            for (int r = 0; r < 4; ++r) acc[mi][ni][r] = 0.f;

    #pragma unroll
    for (int q = 0; q < 2; ++q) {
        int kg = q*32 + sko;
        glds16(A  + (size_t)(m0 + rowA0)*K + kg, As + q*4096 + s0*512 + l*8);
        glds16(A  + (size_t)(m0 + rowA1)*K + kg, As + q*4096 + s1*512 + l*8);
        glds16(BT + (size_t)(n0 + rowA0)*K + kg, Bs + q*4096 + s0*512 + l*8);
        glds16(BT + (size_t)(n0 + rowA1)*K + kg, Bs + q*4096 + s1*512 + l*8);
    }
    __syncthreads();
    #pragma unroll
    for (int q = 0; q < 2; ++q) {
        bf16x8 af[4], bf[4];
        #pragma unroll
        for (int mi = 0; mi < 4; ++mi)
            af[mi] = *(const bf16x8*)(As + q*4096 + (wm*64 + mi*16 + lr)*32 + lq*8);
        #pragma unroll
        for (int ni = 0; ni < 4; ++ni)
            bf[ni] = *(const bf16x8*)(Bs + q*4096 + (wn*64 + ni*16 + lr)*32 + lq*8);
        #pragma unroll
        for (int mi = 0; mi < 4; ++mi)
            #pragma unroll
            for (int ni = 0; ni < 4; ++ni)
                acc[mi][ni] = __builtin_amdgcn_mfma_f32_16x16x32_bf16(af[mi], bf[ni], acc[mi][ni], 0, 0, 0);
    }

    // epilogue: rows of this block are j = 0..127 (p0 multiple of 128), i constant
    int p0 = pofs + m0;
    int bi = p0 >> 7;            // b*NP + i
    int b  = bi >> 7;
    const unsigned short* Ubase = U + (size_t)b*NP*D;
    const unsigned short* Vrow  = V + (size_t)bi*D;
    #pragma unroll
    for (int ni = 0; ni < 4; ++ni) {
        int gc = n0 + wn*64 + ni*16 + lr;
        float add = b2f(Vrow[gc]) + b1[gc];
        #pragma unroll
        for (int mi = 0; mi < 4; ++mi) {
            int row = wm*64 + mi*16 + lq*4;
            #pragma unroll
            for (int r = 0; r < 4; ++r) {
                float u = b2f(Ubase[(size_t)(row + r)*D + gc]);
                float val = acc[mi][ni][r] + u + add;
                h1c[(size_t)(m0 + row + r)*D + gc] = f2b(relu_(val));
            }
        }
    }
}

// ---------------- final heads -> sigmoid, f32 out ----------------
__global__ __launch_bounds__(256) void k_final(const float* __restrict__ x,
    const float* __restrict__ subject, const float* __restrict__ obj,
    const float* __restrict__ cs_w, const float* __restrict__ cs_b,
    const float* __restrict__ cso_w, const float* __restrict__ cso_b,
    float* __restrict__ out)
{
    int bi = blockIdx.x;
    int b  = bi >> 7;
    const float* xr = x + (size_t)bi*D;
    const float* sb = subject + (size_t)b*D;
    const float* ob = obj + (size_t)b*D;
    int tid = threadIdx.x;
    float a0 = 0.f, a1 = 0.f;
    for (int k = tid; k < D; k += 256) {
        float xv = xr[k];
        a0 = fmaf(xv, cs_w[k], a0);
        a0 = fmaf(sb[k], cs_w[D+k], a0);
        a1 = fmaf(xv, cso_w[k], a1);
        a1 = fmaf(ob[k], cso_w[D+k], a1);
    }
    __shared__ float r0[256], r1[256];
    r0[tid] = a0; r1[tid] = a1;
    __syncthreads();
    for (int s2 = 128; s2 > 0; s2 >>= 1) {
        if (tid < s2) { r0[tid] += r0[tid+s2]; r1[tid] += r1[tid+s2]; }
        __syncthreads();
    }
    if (tid == 0) {
        out[bi*2+0] = 1.f/(1.f + expf(-(r0[0] + cs_b[0])));
        out[bi*2+1] = 1.f/(1.f + expf(-(r1[0] + cso_b[0])));
    }
}

extern "C" void kernel_launch(void* const* d_in, const int* in_sizes, int n_in,
                              void* d_out, int out_size, void* d_ws, size_t ws_size,
                              hipStream_t stream)
{
    const float* feats   = (const float*)d_in[0];
    const float* subject = (const float*)d_in[1];
    const float* obj     = (const float*)d_in[2];
    const float* prop    = (const float*)d_in[3];
    const float* gp_w1 = (const float*)d_in[4];  const float* gp_b1 = (const float*)d_in[5];
    const float* gp_w2 = (const float*)d_in[6];  const float* gp_b2 = (const float*)d_in[7];
    const float* gp_w3 = (const float*)d_in[8];  const float* gp_b3 = (const float*)d_in[9];
    const float* pm_w1 = (const float*)d_in[10]; const float* pm_b1 = (const float*)d_in[11];
    const float* pm_w2 = (const float*)d_in[12]; const float* pm_b2 = (const float*)d_in[13];
    const float* pm_w3 = (const float*)d_in[14]; const float* pm_b3 = (const float*)d_in[15];
    const float* ag_w1 = (const float*)d_in[16]; const float* ag_b1 = (const float*)d_in[17];
    const float* ag_w2 = (const float*)d_in[18]; const float* ag_b2 = (const float*)d_in[19];
    const float* ag_w3 = (const float*)d_in[20]; const float* ag_b3 = (const float*)d_in[21];
    const float* cs_w  = (const float*)d_in[22]; const float* cs_b  = (const float*)d_in[23];
    const float* cso_w = (const float*)d_in[24]; const float* cso_b = (const float*)d_in[25];
    float* out = (float*)d_out;

    const int M = BS*NP;          // 256
    const int MN = M*D;           // 262144

    // ---- workspace layout (bytes). Cp aliases the chunk region ----
    char* wsb = (char*)d_ws;
    size_t off = 0;
    auto alloc = [&](size_t bytes) { char* p = wsb + off; off += (bytes + 255) & ~255ull; return p; };
    unsigned short* Ub = (unsigned short*)alloc((size_t)MN*2);
    unsigned short* Vb = (unsigned short*)alloc((size_t)MN*2);
    float* red = (float*)alloc((size_t)MN*4);
    float* xf  = (float*)alloc((size_t)MN*4);
    unsigned short* xh1b = (unsigned short*)alloc((size_t)MN*2);
    unsigned short* xh2b = (unsigned short*)alloc((size_t)MN*2);
    unsigned short* w1aT = (unsigned short*)alloc((size_t)D*D*2);
    unsigned short* w1bT = (unsigned short*)alloc((size_t)D*D*2);
    unsigned short* w1cT = (unsigned short*)alloc((size_t)D*GEO*2);
    unsigned short* w2T  = (unsigned short*)alloc((size_t)D*D*2);
    unsigned short* w3T  = (unsigned short*)alloc((size_t)D*D*2);
    unsigned short* agw1T= (unsigned short*)alloc((size_t)2*D*D*2);
    unsigned short* agw2T= (unsigned short*)alloc((size_t)D*D*2);
    unsigned short* agw3T= (unsigned short*)alloc((size_t)D*D*2);
    size_t persist = off;

    // shared region: Cp (split-K partials, phases 1&3) ALIASES chunk bufs (phase 2)
    size_t cp_bytes = (size_t)8*MN*4;                              // 8.4 MB
    size_t chunk_unit = (size_t)NP*(GEO*2 + D*2 + D*2);            // geo,h1,h2
    int CH = M;  // try the whole problem in one chunk
    while (CH > 2) {
        size_t region = (size_t)CH*chunk_unit;
        if (region < cp_bytes) region = cp_bytes;
        if (persist + region + 4096 <= ws_size) break;
        CH >>= 1;
    }
    float*          Cp    = (float*)(wsb + persist);
    unsigned short* geoPc = (unsigned short*)(wsb + persist);
    unsigned short* h1c   = geoPc + (size_t)CH*NP*GEO;
    unsigned short* h2c   = h1c   + (size_t)CH*NP*D;

    // 0) all weight transposes + bf16 in one dispatch (incl. W1c geo slice)
    WT8 d;
    d.src[0]=pm_w1;                d.dst[0]=w1aT;  d.kt[0]=16;
    d.src[1]=pm_w1+(size_t)D*D;    d.dst[1]=w1bT;  d.kt[1]=16;
    d.src[2]=pm_w1+(size_t)2*D*D;  d.dst[2]=w1cT;  d.kt[2]=1;
    d.src[3]=pm_w2;                d.dst[3]=w2T;   d.kt[3]=16;
    d.src[4]=pm_w3;                d.dst[4]=w3T;   d.kt[4]=16;
    d.src[5]=ag_w1;                d.dst[5]=agw1T; d.kt[5]=32;
    d.src[6]=ag_w2;                d.dst[6]=agw2T; d.kt[6]=16;
    d.src[7]=ag_w3;                d.dst[7]=agw3T; d.kt[7]=16;
    d.pre[0]=0;
    for (int e = 0; e < 8; ++e) d.pre[e+1] = d.pre[e] + d.kt[e]*16;
    k_wTall<<<d.pre[8], 256, 0, stream>>>(d);

    // 1) U,V = feats @ {w1a, w1b}: split-K MFMA (KZ=4, 2 mats) + reduce (bf16 out)
    k_skmm<true><<<dim3(M/16, D/128, 8), 256, 0, stream>>>(
        feats, nullptr, D, 0, w1aT, w1bT, Cp, 4, 256, D);
    k_red<false,true><<<dim3(MN/1024, 1, 2), 256, 0, stream>>>(
        Cp, 4, nullptr, Ub, Vb, MN, D);

    // 2) chunked over (b,i) rows: geo(MFMA) -> h1(MFMA) -> h2 -> fc+topk fused
    int nchunks = M/CH;
    for (int cchunk = 0; cchunk < nchunks; ++cchunk) {
        int bi0  = cchunk * CH;
        int pofs = bi0 * NP;
        k_geo2<<<CH*NP/256, 256, 0, stream>>>(prop, gp_w1, gp_b1, gp_w2, gp_b2, gp_w3, gp_b3, geoPc, pofs);
        dim3 gBig(CH*NP/128, D/128);
        k_h1m<<<gBig, 256, 0, stream>>>(geoPc, w1cT, pm_b1, Ub, Vb, h1c, pofs);
        dim3 g8(CH*NP/256, D/256);
        k_mgemm8<true ,false><<<g8, 512, 0, stream>>>(h1c, w2T, pm_b2, h2c, CH*NP, D, D);
        k_mgemm8<false,true ><<<g8, 512, 0, stream>>>(h2c, w3T, pm_b3, red + (size_t)bi0*D, CH*NP, D, D);
    }

    // 3) aggregate MLP via split-K MFMA + fused reduce/activation
    k_skmm<true><<<dim3(M/16, D/128, 8), 256, 0, stream>>>(
        feats, red, D, D, agw1T, nullptr, Cp, 8, 256, D);
    k_red<true,true><<<dim3(MN/1024, 1, 1), 256, 0, stream>>>(
        Cp, 8, ag_b1, xh1b, nullptr, MN, D);
    k_skmm<false><<<dim3(M/16, D/128, 4), 256, 0, stream>>>(
        xh1b, nullptr, D, 0, agw2T, nullptr, Cp, 4, 256, D);
    k_red<true,true><<<dim3(MN/1024, 1, 1), 256, 0, stream>>>(
        Cp, 4, ag_b2, xh2b, nullptr, MN, D);
    k_skmm<false><<<dim3(M/16, D/128, 4), 256, 0, stream>>>(
        xh2b, nullptr, D, 0, agw3T, nullptr, Cp, 4, 256, D);
    k_red<false,false><<<dim3(MN/1024, 1, 1), 256, 0, stream>>>(
        Cp, 4, ag_b3, xf, nullptr, MN, D);

    // 4) sigmoid heads
    k_final<<<M, 256, 0, stream>>>(xf, subject, obj, cs_w, cs_b, cso_w, cso_b, out);
}